// Round 14
// baseline (234.855 us; speedup 1.0000x reference)
//
#include <hip/hip_runtime.h>

#define B_     8
#define N_     16384
#define F_     64
#define E_     262144
#define C_     10
#define NF_    (N_ * F_)        // 1048576
#define BN_    (B_ * N_)        // 131072
#define BNF_   (B_ * N_ * F_)   // 8388608
#define CAP_   48               // padded CSR row capacity; P(Poisson(16) >= 48) ~ 6e-11
#define CHUNK_ 16384            // edges per build workgroup (R14: was 8192)
#define NCH_   (E_ / CHUNK_)    // 16 chunks per batch
#define NW_    (N_ / 4)         // 4096 packed-u8 words per batch
#define NSB_   4096             // gat2 blocks = BN_/32 (stats partial rows)
#define NFB_   1024             // k_final blocks
#define EPS_   1e-5f

typedef _Float16 h8 __attribute__((ext_vector_type(8)));
typedef _Float16 h4 __attribute__((ext_vector_type(4)));
typedef float f32x4 __attribute__((ext_vector_type(4)));

// XOR swizzle for 64-col fp16 LDS tiles accessed as h8 (16B) chunks.
#define SWZ(r, o) ((((r) * 64 + (o))) ^ (((r) & 7) << 3))

// ---------------- Build phase A: per-chunk privatized counts ----------------
// LEDGER: R2 global-atomic build 4.4x slower (cross-XCD L2). R4 threadfence
// ticket ~140us. R6 cache-traffic cuts neutral. R7 co-schedule neutral.
// R8/R9 degree-sort net-negative. R10 leaner SEG + 8 waves/SIMD: best 225.8.
// R12 NT hints -6us REVERTED. R13 zero-row pad neutral REVERTED.
// R14: CHUNK_ 16384 — halve partials traffic + k_offsets serial chain.
__global__ __launch_bounds__(256) void k_count(const int* __restrict__ src,
                                               const int* __restrict__ dst,
                                               unsigned int* __restrict__ partO,
                                               unsigned int* __restrict__ partI,
                                               const float* __restrict__ W1,
                                               const float* __restrict__ W2,
                                               _Float16* __restrict__ Wt1,
                                               _Float16* __restrict__ Wt2) {
    __shared__ unsigned int pO[NW_];  // 16 KB
    __shared__ unsigned int pI[NW_];  // 16 KB
    int t = threadIdx.x;
    if (blockIdx.x >= B_ * NCH_) {    // W-transpose prep, 16 tail blocks
        int g = blockIdx.x - B_ * NCH_;          // 0..15
        const float* Ws = (g & 8) ? W2 : W1;
        _Float16* Wd = (g & 8) ? Wt2 : Wt1;
        int c0 = (g & 7) * 512;
        for (int j = t; j < 512; j += 256) {
            int o = c0 + j;                      // Wt flat idx: f*64 + k
            Wd[o] = (_Float16)Ws[(o & 63) * 64 + (o >> 6)];
        }
        return;
    }
    int b = blockIdx.x & 7, c = blockIdx.x >> 3;
    for (int i = t; i < NW_; i += 256) { pO[i] = 0; pI[i] = 0; }
    __syncthreads();
    const int4* sb = (const int4*)(src + (size_t)b * E_ + (size_t)c * CHUNK_);
    const int4* db = (const int4*)(dst + (size_t)b * E_ + (size_t)c * CHUNK_);
#pragma unroll
    for (int j = 0; j < CHUNK_ / 1024; ++j) {   // 16 x int4 per thread
        int4 s4 = sb[t + j * 256];
        int4 d4 = db[t + j * 256];
#pragma unroll
        for (int k = 0; k < 4; ++k) {
            int s = ((const int*)&s4)[k];
            int d = ((const int*)&d4)[k];
            atomicAdd(&pO[s >> 2], 1u << ((s & 3) * 8));
            atomicAdd(&pI[d >> 2], 1u << ((d & 3) * 8));
        }
    }
    __syncthreads();
    size_t base = (size_t)(b * NCH_ + c) * NW_;
    for (int i = t; i < NW_; i += 256) {
        partO[base + i] = pO[i];
        partI[base + i] = pI[i];
    }
}

// ---------------- Build phase B: packed prefix over chunks + degrees --------
__global__ __launch_bounds__(256) void k_offsets(const unsigned int* __restrict__ partO,
                                                 const unsigned int* __restrict__ partI,
                                                 unsigned int* __restrict__ baseArr,
                                                 float* __restrict__ degOr,
                                                 float* __restrict__ degIr,
                                                 int* __restrict__ cntI_g) {
    int gw = blockIdx.x * 256 + threadIdx.x;  // word id in [0, BN_/4)
    int b = gw >> 12;
    int rw = gw & 4095;
    unsigned int sumI = 0, sumO = 0;
#pragma unroll 8
    for (int c = 0; c < NCH_; ++c) {
        size_t idx = (size_t)(b * NCH_ + c) * NW_ + rw;
        unsigned int wI = partI[idx];
        baseArr[idx] = sumI;  // exclusive prefix, packed u8 lanes
        sumI += wI;
        sumO += partO[idx];
    }
    int row0 = gw * 4;
#pragma unroll
    for (int r = 0; r < 4; ++r) {
        unsigned int ci = (sumI >> (r * 8)) & 0xFFu;
        unsigned int co = (sumO >> (r * 8)) & 0xFFu;
        degIr[row0 + r] = rsqrtf(fmaxf((float)ci, 1.0f));
        degOr[row0 + r] = rsqrtf(fmaxf((float)co, 1.0f));
        cntI_g[row0 + r] = (int)ci;
    }
}

// ---------------- Combined CSR fill + conv1 MFMA mm (co-schedule) -----------
// Blocks [0,128): fill role (32 KB LDS). Blocks [128,2176): mm role
// (16 KB LDS): z1 = fp16(degOr * x @ Wt1).
__global__ __launch_bounds__(256) void k_fillmm(
        const int* __restrict__ src, const int* __restrict__ dst,
        const unsigned int* __restrict__ baseArr, unsigned short* __restrict__ csr,
        const float* __restrict__ x, const _Float16* __restrict__ Wt,
        const float* __restrict__ rs, _Float16* __restrict__ out) {
    __shared__ char smem[32768];
    int t = threadIdx.x;

    if (blockIdx.x < B_ * NCH_) {  // ---- fill role ----
        unsigned int* cur = (unsigned int*)smem;          // 16 KB
        unsigned int* bw  = cur + NW_;                    // 16 KB
        int b = blockIdx.x & 7, c = blockIdx.x >> 3;
        size_t pbase = (size_t)(b * NCH_ + c) * NW_;
        for (int i = t; i < NW_; i += 256) { cur[i] = 0; bw[i] = baseArr[pbase + i]; }
        __syncthreads();
        const int4* sb = (const int4*)(src + (size_t)b * E_ + (size_t)c * CHUNK_);
        const int4* db = (const int4*)(dst + (size_t)b * E_ + (size_t)c * CHUNK_);
        unsigned short* cb = csr + (size_t)b * N_ * CAP_;
#pragma unroll
        for (int j = 0; j < CHUNK_ / 1024; ++j) {
            int4 s4 = sb[t + j * 256];
            int4 d4 = db[t + j * 256];
#pragma unroll
            for (int k = 0; k < 4; ++k) {
                int s = ((const int*)&s4)[k];
                int d = ((const int*)&d4)[k];
                unsigned int sh = (d & 3) * 8;
                unsigned int old = atomicAdd(&cur[d >> 2], 1u << sh);
                unsigned int pos = ((old >> sh) & 0xFFu) + ((bw[d >> 2] >> sh) & 0xFFu);
                if (pos < CAP_) cb[(size_t)d * CAP_ + pos] = (unsigned short)s;
            }
        }
        return;
    }

    // ---- mm role: conv1 dense mm, fp32 in, SCALE=degOr ----
    _Float16* Al = (_Float16*)smem;        // 8 KB, Wt swizzled
    _Float16* Bl = Al + 4096;              // 8 KB, input rows swizzled
    int g = blockIdx.x - B_ * NCH_;
    int bat = g & 7;
    int rowg = bat * N_ + (g >> 3) * 64;

#pragma unroll
    for (int j = 0; j < 2; ++j) {  // stage Wt: 512 h8-chunks
        int c = t + j * 256;
        int r = c >> 3, o = (c & 7) * 8;
        *(h8*)&Al[SWZ(r, o)] = *(const h8*)(Wt + c * 8);
    }
#pragma unroll
    for (int j = 0; j < 2; ++j) {  // stage input rows, cvt fp32->fp16
        int c = t + j * 256;
        int r = c >> 3, o = (c & 7) * 8;
        const float4* p = (const float4*)(x + (size_t)(rowg + r) * 64 + o);
        float4 x0 = p[0], x1 = p[1];
        h8 v;
        v[0] = (_Float16)x0.x; v[1] = (_Float16)x0.y;
        v[2] = (_Float16)x0.z; v[3] = (_Float16)x0.w;
        v[4] = (_Float16)x1.x; v[5] = (_Float16)x1.y;
        v[6] = (_Float16)x1.z; v[7] = (_Float16)x1.w;
        *(h8*)&Bl[SWZ(r, o)] = v;
    }
    __syncthreads();

    int lane = t & 63;
    int w = t >> 6;                // wave = f-tile (16 f's)
    int lm = lane & 15;
    int lk = (lane >> 4) * 8;
    f32x4 acc0 = {0.f, 0.f, 0.f, 0.f}, acc1 = {0.f, 0.f, 0.f, 0.f};
    f32x4 acc2 = {0.f, 0.f, 0.f, 0.f}, acc3 = {0.f, 0.f, 0.f, 0.f};
#pragma unroll
    for (int ks = 0; ks < 2; ++ks) {
        h8 a = *(const h8*)&Al[SWZ(w * 16 + lm, lk + ks * 32)];
        h8 vb0 = *(const h8*)&Bl[SWZ(0 + lm, lk + ks * 32)];
        h8 vb1 = *(const h8*)&Bl[SWZ(16 + lm, lk + ks * 32)];
        h8 vb2 = *(const h8*)&Bl[SWZ(32 + lm, lk + ks * 32)];
        h8 vb3 = *(const h8*)&Bl[SWZ(48 + lm, lk + ks * 32)];
        acc0 = __builtin_amdgcn_mfma_f32_16x16x32_f16(a, vb0, acc0, 0, 0, 0);
        acc1 = __builtin_amdgcn_mfma_f32_16x16x32_f16(a, vb1, acc1, 0, 0, 0);
        acc2 = __builtin_amdgcn_mfma_f32_16x16x32_f16(a, vb2, acc2, 0, 0, 0);
        acc3 = __builtin_amdgcn_mfma_f32_16x16x32_f16(a, vb3, acc3, 0, 0, 0);
    }
    int fo = w * 16 + (lane >> 4) * 4;
#define STORE_TILE(ACC, RT)                                                    \
    {                                                                          \
        int row = rowg + (RT) * 16 + lm;                                       \
        float scv = rs[row];                                                   \
        h4 ov;                                                                 \
        ov[0] = (_Float16)(ACC[0] * scv); ov[1] = (_Float16)(ACC[1] * scv);    \
        ov[2] = (_Float16)(ACC[2] * scv); ov[3] = (_Float16)(ACC[3] * scv);    \
        *(h4*)(out + (size_t)row * 64 + fo) = ov;                              \
    }
    STORE_TILE(acc0, 0)
    STORE_TILE(acc1, 1)
    STORE_TILE(acc2, 2)
    STORE_TILE(acc3, 3)
#undef STORE_TILE
}

// Gather SEG macro shared by k_gmm / k_gat. Two 4-deep halves — peak live h8
// temporaries 4 (fits 8 waves/SIMD). Add tree bit-exact vs 8-deep:
// ((v0+v1)+(v2+v3)) + ((v4+v5)+(v6+v7)). Predicated csr load upstream:
// lane c8 loaded its uint4 iff c8*8 < n; SEG(KOFF) consumes source lane
// KOFF/8 only when rem>0 <=> KOFF<n. Garbage slots masked to [0,16384).
#define GAT_SEG(KOFF)                                                          \
    {                                                                          \
        int rem = n - (KOFF);                                                  \
        int srcl = lb + ((KOFF) >> 3);                                         \
        unsigned ddA0 = __shfl(ev.x, srcl), ddA1 = __shfl(ev.y, srcl);         \
        h8 v[4];                                                               \
        _Pragma("unroll")                                                      \
        for (int jj = 0; jj < 4; ++jj) {                                       \
            unsigned dw = (jj < 2) ? ddA0 : ddA1;                              \
            int s = (int)((dw >> ((jj & 1) * 16)) & 0x3FFFu);                  \
            h8 vv = {};                                                        \
            if (jj < rem) vv = *(const h8*)(zb + s * 64 + ho);                 \
            v[jj] = vv;                                                        \
        }                                                                      \
        h8 t0 = (v[0] + v[1]) + (v[2] + v[3]);                                 \
        unsigned ddB0 = __shfl(ev.z, srcl), ddB1 = __shfl(ev.w, srcl);         \
        _Pragma("unroll")                                                      \
        for (int jj = 0; jj < 4; ++jj) {                                       \
            unsigned dw = (jj < 2) ? ddB0 : ddB1;                              \
            int s = (int)((dw >> ((jj & 1) * 16)) & 0x3FFFu);                  \
            h8 vv = {};                                                        \
            if (jj + 4 < rem) vv = *(const h8*)(zb + s * 64 + ho);             \
            v[jj] = vv;                                                        \
        }                                                                      \
        h8 t1 = (v[0] + v[1]) + (v[2] + v[3]);                                 \
        h8 t = t0 + t1;                                                        \
        _Pragma("unroll")                                                      \
        for (int i = 0; i < 8; ++i) af[i] += (float)t[i];                      \
    }

// ---------------- Fused conv1-gather + conv2-mm -----------------------------
__global__ __launch_bounds__(256, 8) void k_gmm(
        const int* __restrict__ cnt, const unsigned short* __restrict__ csr,
        const _Float16* __restrict__ z, const float* __restrict__ degIr,
        const float* __restrict__ degOr, const float* __restrict__ bias,
        const _Float16* __restrict__ Wt2, _Float16* __restrict__ out) {
    __shared__ _Float16 Al[4096];  // Wt2, swizzled
    __shared__ _Float16 Bl[2048];  // 32 h1 rows, swizzled
    int t = threadIdx.x;
    int lane = t & 63;
    int wave = t >> 6;
    int c8 = lane & 7;
    int b = blockIdx.x & 7;
    int rl = wave * 8 + (lane >> 3);          // row within block, 0..31
    int row0 = (blockIdx.x >> 3) * 32;
    int wid = b * N_ + row0 + rl;
    const _Float16* zb = z + (size_t)b * NF_;
    int lb = lane & 56;
    int ho = c8 * 8;

#pragma unroll
    for (int j = 0; j < 2; ++j) {  // stage Wt2 while gather loads fly
        int c = t + j * 256;
        int r = c >> 3, o = (c & 7) * 8;
        *(h8*)&Al[SWZ(r, o)] = *(const h8*)(Wt2 + c * 8);
    }

    int n = cnt[wid];
    if (n > CAP_) n = CAP_;
    size_t cb = (size_t)wid * CAP_;
    uint4 ev = {0u, 0u, 0u, 0u};
    if (c8 * 8 < n) ev = *(const uint4*)(csr + cb + c8 * 8);
    int m = n;
    m = max(m, __shfl_xor(m, 8));
    m = max(m, __shfl_xor(m, 16));
    m = max(m, __shfl_xor(m, 32));

    float af[8];
#pragma unroll
    for (int i = 0; i < 8; ++i) af[i] = 0.0f;
    GAT_SEG(0)
    if (m > 8)  GAT_SEG(8)
    if (m > 16) GAT_SEG(16)
    if (m > 24) GAT_SEG(24)
    if (m > 32) GAT_SEG(32)
    if (m > 40) GAT_SEG(40)

    float dIr = degIr[wid];
    float po = degOr[wid];
    float4 bv0 = *(const float4*)(bias + ho);
    float4 bv1 = *(const float4*)(bias + ho + 4);
    float bb[8] = {bv0.x, bv0.y, bv0.z, bv0.w, bv1.x, bv1.y, bv1.z, bv1.w};
    h8 ov;
#pragma unroll
    for (int i = 0; i < 8; ++i) {
        ov[i] = (_Float16)(fmaxf(fmaf(af[i], dIr, bb[i]), 0.0f) * po);
    }
    *(h8*)&Bl[SWZ(rl, ho)] = ov;
    __syncthreads();

    // mm phase: wave w computes f-tile w*16 for 2 row-tiles of 16
    int lm = lane & 15;
    int lk = (lane >> 4) * 8;
    f32x4 acc0 = {0.f, 0.f, 0.f, 0.f}, acc1 = {0.f, 0.f, 0.f, 0.f};
#pragma unroll
    for (int ks = 0; ks < 2; ++ks) {
        h8 a  = *(const h8*)&Al[SWZ(wave * 16 + lm, lk + ks * 32)];
        h8 v0 = *(const h8*)&Bl[SWZ(lm, lk + ks * 32)];
        h8 v1 = *(const h8*)&Bl[SWZ(16 + lm, lk + ks * 32)];
        acc0 = __builtin_amdgcn_mfma_f32_16x16x32_f16(a, v0, acc0, 0, 0, 0);
        acc1 = __builtin_amdgcn_mfma_f32_16x16x32_f16(a, v1, acc1, 0, 0, 0);
    }
    int fo = wave * 16 + (lane >> 4) * 4;
    int rowg = b * N_ + row0;
    h4 o0, o1;
    o0[0] = (_Float16)acc0[0]; o0[1] = (_Float16)acc0[1];
    o0[2] = (_Float16)acc0[2]; o0[3] = (_Float16)acc0[3];
    o1[0] = (_Float16)acc1[0]; o1[1] = (_Float16)acc1[1];
    o1[2] = (_Float16)acc1[2]; o1[3] = (_Float16)acc1[3];
    *(h4*)(out + (size_t)(rowg + lm) * 64 + fo) = o0;
    *(h4*)(out + (size_t)(rowg + 16 + lm) * 64 + fo) = o1;
}

// ---------------- conv2 gather + fused BN-stats partials --------------------
__global__ __launch_bounds__(256, 8) void k_gat(
        const int* __restrict__ cnt, const unsigned short* __restrict__ csr,
        const _Float16* __restrict__ z, const float* __restrict__ degIr,
        const float* __restrict__ bias, _Float16* __restrict__ out16,
        float* __restrict__ pstat) {
    __shared__ float sS[4][64];
    __shared__ float sQ[4][64];
    int t = threadIdx.x;
    int lane = t & 63;
    int wave = t >> 6;
    int c8 = lane & 7;
    int b = blockIdx.x & 7;
    int row = (blockIdx.x >> 3) * 32 + wave * 8 + (lane >> 3);
    int wid = b * N_ + row;
    const _Float16* zb = z + (size_t)b * NF_;
    int lb = lane & 56;
    int ho = c8 * 8;

    int n = cnt[wid];
    if (n > CAP_) n = CAP_;
    size_t cb = (size_t)wid * CAP_;
    uint4 ev = {0u, 0u, 0u, 0u};
    if (c8 * 8 < n) ev = *(const uint4*)(csr + cb + c8 * 8);
    int m = n;
    m = max(m, __shfl_xor(m, 8));
    m = max(m, __shfl_xor(m, 16));
    m = max(m, __shfl_xor(m, 32));

    float af[8];
#pragma unroll
    for (int i = 0; i < 8; ++i) af[i] = 0.0f;
    GAT_SEG(0)
    if (m > 8)  GAT_SEG(8)
    if (m > 16) GAT_SEG(16)
    if (m > 24) GAT_SEG(24)
    if (m > 32) GAT_SEG(32)
    if (m > 40) GAT_SEG(40)

    float dIr = degIr[wid];
    float4 bv0 = *(const float4*)(bias + ho);
    float4 bv1 = *(const float4*)(bias + ho + 4);
    float bb[8] = {bv0.x, bv0.y, bv0.z, bv0.w, bv1.x, bv1.y, bv1.z, bv1.w};
    float vv[8];
    h8 ov;
#pragma unroll
    for (int i = 0; i < 8; ++i) {
        vv[i] = fmaf(af[i], dIr, bb[i]);
        ov[i] = (_Float16)vv[i];
    }
    *(h8*)(out16 + (size_t)wid * 64 + ho) = ov;
    float ssv[8], qqv[8];
#pragma unroll
    for (int i = 0; i < 8; ++i) { ssv[i] = vv[i]; qqv[i] = vv[i] * vv[i]; }
#pragma unroll
    for (int i = 0; i < 8; ++i) {
        ssv[i] += __shfl_xor(ssv[i], 8);  qqv[i] += __shfl_xor(qqv[i], 8);
        ssv[i] += __shfl_xor(ssv[i], 16); qqv[i] += __shfl_xor(qqv[i], 16);
        ssv[i] += __shfl_xor(ssv[i], 32); qqv[i] += __shfl_xor(qqv[i], 32);
    }
    if (lane < 8) {
#pragma unroll
        for (int i = 0; i < 8; ++i) {
            sS[wave][lane * 8 + i] = ssv[i];
            sQ[wave][lane * 8 + i] = qqv[i];
        }
    }
    __syncthreads();
    if (t < 64) {
        float s_ = sS[0][t] + sS[1][t] + sS[2][t] + sS[3][t];
        float q_ = sQ[0][t] + sQ[1][t] + sQ[2][t] + sQ[3][t];
        pstat[(size_t)blockIdx.x * 128 + t] = s_;
        pstat[(size_t)blockIdx.x * 128 + 64 + t] = q_;
    }
}

// ---------------- reduce stats partials: [4096][128] -> stats2[32][128] -----
__global__ __launch_bounds__(256) void k_red(const float* __restrict__ part,
                                             float* __restrict__ stats2) {
    __shared__ float sred[256];
    int t = threadIdx.x;
    int half = t >> 7;   // 0/1
    int s = t & 127;     // stat id
    int r0 = blockIdx.x * (NSB_ / 32);  // 128 rows per block
    float acc = 0.0f;
    for (int k = 0; k < NSB_ / 32 / 2; ++k) {
        acc += part[(size_t)(r0 + k * 2 + half) * 128 + s];
    }
    sred[t] = acc;
    __syncthreads();
    if (t < 128) stats2[blockIdx.x * 128 + t] = sred[t] + sred[t + 128];
}

// ---------------- fused BN-coeff + BN-apply + final linear ------------------
// NOTE (R4): no threadfence-ticket fsum fusion — device-scope fence ~140 us.
__global__ __launch_bounds__(256) void k_final(
        const _Float16* __restrict__ h, const float* __restrict__ linW,
        const float* __restrict__ stats2, const float* __restrict__ gamma,
        const float* __restrict__ beta, float* __restrict__ pf) {
    __shared__ float pre[256];
    __shared__ float scs[64], shs[64];
    int t = threadIdx.x;
    {   // all 256 threads: stat u = t&127, j-half = t>>7 (16 iters each)
        int u = t & 127, jh = t >> 7;
        float a = 0.0f;
#pragma unroll
        for (int j = 0; j < 16; ++j) a += stats2[(jh * 16 + j) * 128 + u];
        pre[t] = a;
    }
    __syncthreads();
    if (t < 64) {
        float sum = pre[t] + pre[t + 128];
        float sq  = pre[t + 64] + pre[t + 192];
        float inv = 1.0f / (float)BN_;
        float mean = sum * inv;
        float var  = sq * inv - mean * mean;
        float s = gamma[t] * rsqrtf(var + EPS_);
        scs[t] = s;
        shs[t] = beta[t] - mean * s;
    }
    __syncthreads();

    int lane = t & 63;
    int wv = t >> 6;
    int b0 = wv * 2, b1 = wv * 2 + 1;
    int base = blockIdx.x * (NF_ / NFB_);  // 1024 per block
    float4 s4  = *(const float4*)&scs[(lane & 15) * 4];
    float4 sh4 = *(const float4*)&shs[(lane & 15) * 4];
    float acc[C_][2];
#pragma unroll
    for (int c = 0; c < C_; ++c) { acc[c][0] = 0.0f; acc[c][1] = 0.0f; }

#pragma unroll
    for (int k = 0; k < 4; ++k) {
        int i = base + k * 256 + lane * 4;  // 4 consecutive channels/thread
        h4 ha = *(const h4*)(h + (size_t)b0 * NF_ + i);
        h4 hb = *(const h4*)(h + (size_t)b1 * NF_ + i);
        float h0[4], h1[4];
        h0[0] = fmaf((float)ha[0], s4.x, sh4.x);
        h0[1] = fmaf((float)ha[1], s4.y, sh4.y);
        h0[2] = fmaf((float)ha[2], s4.z, sh4.z);
        h0[3] = fmaf((float)ha[3], s4.w, sh4.w);
        h1[0] = fmaf((float)hb[0], s4.x, sh4.x);
        h1[1] = fmaf((float)hb[1], s4.y, sh4.y);
        h1[2] = fmaf((float)hb[2], s4.z, sh4.z);
        h1[3] = fmaf((float)hb[3], s4.w, sh4.w);
#pragma unroll
        for (int c = 0; c < C_; ++c) {
            float4 w4 = *(const float4*)(linW + (size_t)c * NF_ + i);
            float a0 = acc[c][0], a1 = acc[c][1];
            a0 = fmaf(h0[0], w4.x, a0); a0 = fmaf(h0[1], w4.y, a0);
            a0 = fmaf(h0[2], w4.z, a0); a0 = fmaf(h0[3], w4.w, a0);
            a1 = fmaf(h1[0], w4.x, a1); a1 = fmaf(h1[1], w4.y, a1);
            a1 = fmaf(h1[2], w4.z, a1); a1 = fmaf(h1[3], w4.w, a1);
            acc[c][0] = a0; acc[c][1] = a1;
        }
    }

#pragma unroll
    for (int c = 0; c < C_; ++c) {
#pragma unroll
        for (int j = 0; j < 2; ++j) {
            float v = acc[c][j];
            v += __shfl_down(v, 32);
            v += __shfl_down(v, 16);
            v += __shfl_down(v, 8);
            v += __shfl_down(v, 4);
            v += __shfl_down(v, 2);
            v += __shfl_down(v, 1);
            acc[c][j] = v;
        }
    }
    if (lane == 0) {
        float* p = pf + (size_t)blockIdx.x * 80;
#pragma unroll
        for (int c = 0; c < C_; ++c) {
            p[b0 * C_ + c] = acc[c][0];
            p[b1 * C_ + c] = acc[c][1];
        }
    }
}

// ---------------- final sum: pf[1024][80] -> out[80] ------------------------
__global__ __launch_bounds__(64) void k_fsum(const float* __restrict__ pf,
                                             const float* __restrict__ linb,
                                             float* __restrict__ out) {
    int o = blockIdx.x;        // 0..79 = b*10+c
    int lane = threadIdx.x;
    float acc = 0.0f;
#pragma unroll
    for (int k = 0; k < 16; ++k) {
        acc += pf[(size_t)(k * 64 + lane) * 80 + o];
    }
    acc += __shfl_down(acc, 32);
    acc += __shfl_down(acc, 16);
    acc += __shfl_down(acc, 8);
    acc += __shfl_down(acc, 4);
    acc += __shfl_down(acc, 2);
    acc += __shfl_down(acc, 1);
    if (lane == 0) out[o] = acc + linb[o % C_];
}

extern "C" void kernel_launch(void* const* d_in, const int* in_sizes, int n_in,
                              void* d_out, int out_size, void* d_ws, size_t ws_size,
                              hipStream_t stream) {
    const float* x        = (const float*)d_in[0];
    const int*   edge_src = (const int*)d_in[1];
    const int*   edge_dst = (const int*)d_in[2];
    const float* W1       = (const float*)d_in[3];
    const float* b1       = (const float*)d_in[4];
    const float* W2       = (const float*)d_in[5];
    const float* b2       = (const float*)d_in[6];
    const float* gamma    = (const float*)d_in[7];
    const float* beta     = (const float*)d_in[8];
    const float* linW     = (const float*)d_in[9];
    const float* linb     = (const float*)d_in[10];
    float* out = (float*)d_out;

    char* w = (char*)d_ws;
    float* degOr = (float*)w;           w += BN_ * 4;
    float* degIr = (float*)w;           w += BN_ * 4;
    int*   cntI  = (int*)w;             w += BN_ * 4;
    unsigned short* csr = (unsigned short*)w; w += (size_t)BN_ * CAP_ * 2;
    _Float16* z1   = (_Float16*)w;      w += (size_t)BNF_ * 2;
    _Float16* z2   = (_Float16*)w;      w += (size_t)BNF_ * 2;  // must not alias z1
    _Float16* h2h  = (_Float16*)w;      w += (size_t)BNF_ * 2;
    unsigned int* partO   = (unsigned int*)w;  w += (size_t)B_ * NCH_ * NW_ * 4;
    unsigned int* partI   = (unsigned int*)w;  w += (size_t)B_ * NCH_ * NW_ * 4;
    unsigned int* baseArr = (unsigned int*)w;  w += (size_t)B_ * NCH_ * NW_ * 4;
    float* partStats = (float*)w;       w += (size_t)NSB_ * 128 * 4;
    float* stats2 = (float*)w;          w += 32 * 128 * 4;
    float* pf    = (float*)w;           w += (size_t)NFB_ * 80 * 4;
    _Float16* Wt1 = (_Float16*)w;       w += 4096 * 2;
    _Float16* Wt2 = (_Float16*)w;       w += 4096 * 2;

    // CSR build + degrees (W-transpose prep folded into k_count tail blocks)
    k_count<<<B_ * NCH_ + 16, 256, 0, stream>>>(edge_src, edge_dst, partO, partI,
                                                W1, W2, Wt1, Wt2);
    k_offsets<<<BN_ / 4 / 256, 256, 0, stream>>>(partO, partI, baseArr, degOr, degIr, cntI);

    // Co-scheduled: CSR fill (blocks 0..127) || conv1 mm (blocks 128..2175)
    k_fillmm<<<B_ * NCH_ + BN_ / 64, 256, 0, stream>>>(edge_src, edge_dst, baseArr,
                                                       csr, x, Wt1, degOr, z1);

    // fused conv1-gather + conv2-mm: z2 = fp16(h1 @ W2)
    k_gmm<<<BN_ / 32, 256, 0, stream>>>(cntI, csr, z1, degIr, degOr, b1, Wt2, z2);
    // conv2 gather: h2 = fp16(gather(z2)*dIr + b2) + BN-stats partials
    k_gat<<<BN_ / 32, 256, 0, stream>>>(cntI, csr, z2, degIr, b2, h2h, partStats);

    // BN stats reduce + fused BN/linear + final sum
    k_red<<<32, 256, 0, stream>>>(partStats, stats2);
    k_final<<<NFB_, 256, 0, stream>>>(h2h, linW, stats2, gamma, beta, pf);
    k_fsum<<<80, 64, 0, stream>>>(pf, linb, out);
}

// Round 15
// 225.486 us; speedup vs baseline: 1.0416x; 1.0416x over previous
//
#include <hip/hip_runtime.h>

#define B_     8
#define N_     16384
#define F_     64
#define E_     262144
#define C_     10
#define NF_    (N_ * F_)        // 1048576
#define BN_    (B_ * N_)        // 131072
#define BNF_   (B_ * N_ * F_)   // 8388608
#define CAP_   48               // padded CSR row capacity; P(Poisson(16) >= 48) ~ 6e-11
#define CHUNK_ 8192             // edges per build workgroup (R14's 16384 regressed: fill/count drop to 128 blocks)
#define NCH_   (E_ / CHUNK_)    // 32 chunks per batch
#define NW_    (N_ / 4)         // 4096 packed-u8 words per batch
#define NSB_   4096             // gat2 blocks = BN_/32 (stats partial rows)
#define NFB_   1024             // k_final blocks
#define EPS_   1e-5f

typedef _Float16 h8 __attribute__((ext_vector_type(8)));
typedef _Float16 h4 __attribute__((ext_vector_type(4)));
typedef float f32x4 __attribute__((ext_vector_type(4)));

// XOR swizzle for 64-col fp16 LDS tiles accessed as h8 (16B) chunks.
#define SWZ(r, o) ((((r) * 64 + (o))) ^ (((r) & 7) << 3))

// ---------------- Build phase A: per-chunk privatized counts ----------------
// FINAL LEDGER (R15 = exact R10 restore, measured best 225.8us):
//   R2  global-atomic build: 4.4x SLOWER (cross-XCD L2 writeback storm)
//   R4  threadfence ticket: ~140us penalty (device-scope fence per block)
//   R6  cache-resident traffic cuts: neutral (L2/L3 absorb intermediates)
//   R7  fill||mm co-schedule: neutral (kept; -1 launch)
//   R8/9 degree-sort: net-negative (scattered stores > SEG savings)
//   R10 lean 4-deep SEG + 8 waves/SIMD: +2us  <- THIS CONFIG
//   R12 nontemporal hints: -6us (gfx950 NT hurts the csr stream)
//   R13 zero-row-padded unconditional gather: neutral (predication not the cost)
//   R14 CHUNK 16384: -9us (fill parallelism halved)
// Remaining time: divergent-gather L1/L2 service + harness poison fill.
__global__ __launch_bounds__(256) void k_count(const int* __restrict__ src,
                                               const int* __restrict__ dst,
                                               unsigned int* __restrict__ partO,
                                               unsigned int* __restrict__ partI,
                                               const float* __restrict__ W1,
                                               const float* __restrict__ W2,
                                               _Float16* __restrict__ Wt1,
                                               _Float16* __restrict__ Wt2) {
    __shared__ unsigned int pO[NW_];  // 16 KB
    __shared__ unsigned int pI[NW_];  // 16 KB
    int t = threadIdx.x;
    if (blockIdx.x >= B_ * NCH_) {    // W-transpose prep, 16 tail blocks
        int g = blockIdx.x - B_ * NCH_;          // 0..15
        const float* Ws = (g & 8) ? W2 : W1;
        _Float16* Wd = (g & 8) ? Wt2 : Wt1;
        int c0 = (g & 7) * 512;
        for (int j = t; j < 512; j += 256) {
            int o = c0 + j;                      // Wt flat idx: f*64 + k
            Wd[o] = (_Float16)Ws[(o & 63) * 64 + (o >> 6)];
        }
        return;
    }
    int b = blockIdx.x & 7, c = blockIdx.x >> 3;
    for (int i = t; i < NW_; i += 256) { pO[i] = 0; pI[i] = 0; }
    __syncthreads();
    const int4* sb = (const int4*)(src + (size_t)b * E_ + (size_t)c * CHUNK_);
    const int4* db = (const int4*)(dst + (size_t)b * E_ + (size_t)c * CHUNK_);
#pragma unroll
    for (int j = 0; j < CHUNK_ / 1024; ++j) {   // 8 x int4 per thread
        int4 s4 = sb[t + j * 256];
        int4 d4 = db[t + j * 256];
#pragma unroll
        for (int k = 0; k < 4; ++k) {
            int s = ((const int*)&s4)[k];
            int d = ((const int*)&d4)[k];
            atomicAdd(&pO[s >> 2], 1u << ((s & 3) * 8));
            atomicAdd(&pI[d >> 2], 1u << ((d & 3) * 8));
        }
    }
    __syncthreads();
    size_t base = (size_t)(b * NCH_ + c) * NW_;
    for (int i = t; i < NW_; i += 256) {
        partO[base + i] = pO[i];
        partI[base + i] = pI[i];
    }
}

// ---------------- Build phase B: packed prefix over chunks + degrees --------
__global__ __launch_bounds__(256) void k_offsets(const unsigned int* __restrict__ partO,
                                                 const unsigned int* __restrict__ partI,
                                                 unsigned int* __restrict__ baseArr,
                                                 float* __restrict__ degOr,
                                                 float* __restrict__ degIr,
                                                 int* __restrict__ cntI_g) {
    int gw = blockIdx.x * 256 + threadIdx.x;  // word id in [0, BN_/4)
    int b = gw >> 12;
    int rw = gw & 4095;
    unsigned int sumI = 0, sumO = 0;
#pragma unroll 8
    for (int c = 0; c < NCH_; ++c) {
        size_t idx = (size_t)(b * NCH_ + c) * NW_ + rw;
        unsigned int wI = partI[idx];
        baseArr[idx] = sumI;  // exclusive prefix, packed u8 lanes
        sumI += wI;
        sumO += partO[idx];
    }
    int row0 = gw * 4;
#pragma unroll
    for (int r = 0; r < 4; ++r) {
        unsigned int ci = (sumI >> (r * 8)) & 0xFFu;
        unsigned int co = (sumO >> (r * 8)) & 0xFFu;
        degIr[row0 + r] = rsqrtf(fmaxf((float)ci, 1.0f));
        degOr[row0 + r] = rsqrtf(fmaxf((float)co, 1.0f));
        cntI_g[row0 + r] = (int)ci;
    }
}

// ---------------- Combined CSR fill + conv1 MFMA mm (co-schedule) -----------
// Blocks [0,256): fill role (32 KB LDS). Blocks [256,2304): mm role
// (16 KB LDS): z1 = fp16(degOr * x @ Wt1).
__global__ __launch_bounds__(256) void k_fillmm(
        const int* __restrict__ src, const int* __restrict__ dst,
        const unsigned int* __restrict__ baseArr, unsigned short* __restrict__ csr,
        const float* __restrict__ x, const _Float16* __restrict__ Wt,
        const float* __restrict__ rs, _Float16* __restrict__ out) {
    __shared__ char smem[32768];
    int t = threadIdx.x;

    if (blockIdx.x < B_ * NCH_) {  // ---- fill role ----
        unsigned int* cur = (unsigned int*)smem;          // 16 KB
        unsigned int* bw  = cur + NW_;                    // 16 KB
        int b = blockIdx.x & 7, c = blockIdx.x >> 3;
        size_t pbase = (size_t)(b * NCH_ + c) * NW_;
        for (int i = t; i < NW_; i += 256) { cur[i] = 0; bw[i] = baseArr[pbase + i]; }
        __syncthreads();
        const int4* sb = (const int4*)(src + (size_t)b * E_ + (size_t)c * CHUNK_);
        const int4* db = (const int4*)(dst + (size_t)b * E_ + (size_t)c * CHUNK_);
        unsigned short* cb = csr + (size_t)b * N_ * CAP_;
#pragma unroll
        for (int j = 0; j < CHUNK_ / 1024; ++j) {
            int4 s4 = sb[t + j * 256];
            int4 d4 = db[t + j * 256];
#pragma unroll
            for (int k = 0; k < 4; ++k) {
                int s = ((const int*)&s4)[k];
                int d = ((const int*)&d4)[k];
                unsigned int sh = (d & 3) * 8;
                unsigned int old = atomicAdd(&cur[d >> 2], 1u << sh);
                unsigned int pos = ((old >> sh) & 0xFFu) + ((bw[d >> 2] >> sh) & 0xFFu);
                if (pos < CAP_) cb[(size_t)d * CAP_ + pos] = (unsigned short)s;
            }
        }
        return;
    }

    // ---- mm role: conv1 dense mm, fp32 in, SCALE=degOr ----
    _Float16* Al = (_Float16*)smem;        // 8 KB, Wt swizzled
    _Float16* Bl = Al + 4096;              // 8 KB, input rows swizzled
    int g = blockIdx.x - B_ * NCH_;
    int bat = g & 7;
    int rowg = bat * N_ + (g >> 3) * 64;

#pragma unroll
    for (int j = 0; j < 2; ++j) {  // stage Wt: 512 h8-chunks
        int c = t + j * 256;
        int r = c >> 3, o = (c & 7) * 8;
        *(h8*)&Al[SWZ(r, o)] = *(const h8*)(Wt + c * 8);
    }
#pragma unroll
    for (int j = 0; j < 2; ++j) {  // stage input rows, cvt fp32->fp16
        int c = t + j * 256;
        int r = c >> 3, o = (c & 7) * 8;
        const float4* p = (const float4*)(x + (size_t)(rowg + r) * 64 + o);
        float4 x0 = p[0], x1 = p[1];
        h8 v;
        v[0] = (_Float16)x0.x; v[1] = (_Float16)x0.y;
        v[2] = (_Float16)x0.z; v[3] = (_Float16)x0.w;
        v[4] = (_Float16)x1.x; v[5] = (_Float16)x1.y;
        v[6] = (_Float16)x1.z; v[7] = (_Float16)x1.w;
        *(h8*)&Bl[SWZ(r, o)] = v;
    }
    __syncthreads();

    int lane = t & 63;
    int w = t >> 6;                // wave = f-tile (16 f's)
    int lm = lane & 15;
    int lk = (lane >> 4) * 8;
    f32x4 acc0 = {0.f, 0.f, 0.f, 0.f}, acc1 = {0.f, 0.f, 0.f, 0.f};
    f32x4 acc2 = {0.f, 0.f, 0.f, 0.f}, acc3 = {0.f, 0.f, 0.f, 0.f};
#pragma unroll
    for (int ks = 0; ks < 2; ++ks) {
        h8 a = *(const h8*)&Al[SWZ(w * 16 + lm, lk + ks * 32)];
        h8 vb0 = *(const h8*)&Bl[SWZ(0 + lm, lk + ks * 32)];
        h8 vb1 = *(const h8*)&Bl[SWZ(16 + lm, lk + ks * 32)];
        h8 vb2 = *(const h8*)&Bl[SWZ(32 + lm, lk + ks * 32)];
        h8 vb3 = *(const h8*)&Bl[SWZ(48 + lm, lk + ks * 32)];
        acc0 = __builtin_amdgcn_mfma_f32_16x16x32_f16(a, vb0, acc0, 0, 0, 0);
        acc1 = __builtin_amdgcn_mfma_f32_16x16x32_f16(a, vb1, acc1, 0, 0, 0);
        acc2 = __builtin_amdgcn_mfma_f32_16x16x32_f16(a, vb2, acc2, 0, 0, 0);
        acc3 = __builtin_amdgcn_mfma_f32_16x16x32_f16(a, vb3, acc3, 0, 0, 0);
    }
    int fo = w * 16 + (lane >> 4) * 4;
#define STORE_TILE(ACC, RT)                                                    \
    {                                                                          \
        int row = rowg + (RT) * 16 + lm;                                       \
        float scv = rs[row];                                                   \
        h4 ov;                                                                 \
        ov[0] = (_Float16)(ACC[0] * scv); ov[1] = (_Float16)(ACC[1] * scv);    \
        ov[2] = (_Float16)(ACC[2] * scv); ov[3] = (_Float16)(ACC[3] * scv);    \
        *(h4*)(out + (size_t)row * 64 + fo) = ov;                              \
    }
    STORE_TILE(acc0, 0)
    STORE_TILE(acc1, 1)
    STORE_TILE(acc2, 2)
    STORE_TILE(acc3, 3)
#undef STORE_TILE
}

// Gather SEG macro shared by k_gmm / k_gat. Two 4-deep halves — peak live
// h8 temporaries 4 (16 VGPR saved vs 8-deep) to fit 8 waves/SIMD. Add tree
// is bit-exact vs 8-deep: ((v0+v1)+(v2+v3)) + ((v4+v5)+(v6+v7)).
// Predicated csr load upstream: lane c8 loaded its uint4 iff c8*8 < n;
// SEG(KOFF) consumes source lane KOFF/8 only when rem>0 <=> KOFF<n.
#define GAT_SEG(KOFF)                                                          \
    {                                                                          \
        int rem = n - (KOFF);                                                  \
        int srcl = lb + ((KOFF) >> 3);                                         \
        unsigned ddA0 = __shfl(ev.x, srcl), ddA1 = __shfl(ev.y, srcl);         \
        h8 v[4];                                                               \
        _Pragma("unroll")                                                      \
        for (int jj = 0; jj < 4; ++jj) {                                       \
            unsigned dw = (jj < 2) ? ddA0 : ddA1;                              \
            int s = (int)((dw >> ((jj & 1) * 16)) & 0x3FFFu);                  \
            h8 vv = {};                                                        \
            if (jj < rem) vv = *(const h8*)(zb + s * 64 + ho);                 \
            v[jj] = vv;                                                        \
        }                                                                      \
        h8 t0 = (v[0] + v[1]) + (v[2] + v[3]);                                 \
        unsigned ddB0 = __shfl(ev.z, srcl), ddB1 = __shfl(ev.w, srcl);         \
        _Pragma("unroll")                                                      \
        for (int jj = 0; jj < 4; ++jj) {                                       \
            unsigned dw = (jj < 2) ? ddB0 : ddB1;                              \
            int s = (int)((dw >> ((jj & 1) * 16)) & 0x3FFFu);                  \
            h8 vv = {};                                                        \
            if (jj + 4 < rem) vv = *(const h8*)(zb + s * 64 + ho);             \
            v[jj] = vv;                                                        \
        }                                                                      \
        h8 t1 = (v[0] + v[1]) + (v[2] + v[3]);                                 \
        h8 t = t0 + t1;                                                        \
        _Pragma("unroll")                                                      \
        for (int i = 0; i < 8; ++i) af[i] += (float)t[i];                      \
    }

// ---------------- Fused conv1-gather + conv2-mm -----------------------------
__global__ __launch_bounds__(256, 8) void k_gmm(
        const int* __restrict__ cnt, const unsigned short* __restrict__ csr,
        const _Float16* __restrict__ z, const float* __restrict__ degIr,
        const float* __restrict__ degOr, const float* __restrict__ bias,
        const _Float16* __restrict__ Wt2, _Float16* __restrict__ out) {
    __shared__ _Float16 Al[4096];  // Wt2, swizzled
    __shared__ _Float16 Bl[2048];  // 32 h1 rows, swizzled
    int t = threadIdx.x;
    int lane = t & 63;
    int wave = t >> 6;
    int c8 = lane & 7;
    int b = blockIdx.x & 7;
    int rl = wave * 8 + (lane >> 3);          // row within block, 0..31
    int row0 = (blockIdx.x >> 3) * 32;
    int wid = b * N_ + row0 + rl;
    const _Float16* zb = z + (size_t)b * NF_;
    int lb = lane & 56;
    int ho = c8 * 8;

#pragma unroll
    for (int j = 0; j < 2; ++j) {  // stage Wt2 while gather loads fly
        int c = t + j * 256;
        int r = c >> 3, o = (c & 7) * 8;
        *(h8*)&Al[SWZ(r, o)] = *(const h8*)(Wt2 + c * 8);
    }

    int n = cnt[wid];
    if (n > CAP_) n = CAP_;
    size_t cb = (size_t)wid * CAP_;
    uint4 ev = {0u, 0u, 0u, 0u};
    if (c8 * 8 < n) ev = *(const uint4*)(csr + cb + c8 * 8);
    int m = n;
    m = max(m, __shfl_xor(m, 8));
    m = max(m, __shfl_xor(m, 16));
    m = max(m, __shfl_xor(m, 32));

    float af[8];
#pragma unroll
    for (int i = 0; i < 8; ++i) af[i] = 0.0f;
    GAT_SEG(0)
    if (m > 8)  GAT_SEG(8)
    if (m > 16) GAT_SEG(16)
    if (m > 24) GAT_SEG(24)
    if (m > 32) GAT_SEG(32)
    if (m > 40) GAT_SEG(40)

    float dIr = degIr[wid];
    float po = degOr[wid];
    float4 bv0 = *(const float4*)(bias + ho);
    float4 bv1 = *(const float4*)(bias + ho + 4);
    float bb[8] = {bv0.x, bv0.y, bv0.z, bv0.w, bv1.x, bv1.y, bv1.z, bv1.w};
    h8 ov;
#pragma unroll
    for (int i = 0; i < 8; ++i) {
        ov[i] = (_Float16)(fmaxf(fmaf(af[i], dIr, bb[i]), 0.0f) * po);
    }
    *(h8*)&Bl[SWZ(rl, ho)] = ov;
    __syncthreads();

    // mm phase: wave w computes f-tile w*16 for 2 row-tiles of 16
    int lm = lane & 15;
    int lk = (lane >> 4) * 8;
    f32x4 acc0 = {0.f, 0.f, 0.f, 0.f}, acc1 = {0.f, 0.f, 0.f, 0.f};
#pragma unroll
    for (int ks = 0; ks < 2; ++ks) {
        h8 a  = *(const h8*)&Al[SWZ(wave * 16 + lm, lk + ks * 32)];
        h8 v0 = *(const h8*)&Bl[SWZ(lm, lk + ks * 32)];
        h8 v1 = *(const h8*)&Bl[SWZ(16 + lm, lk + ks * 32)];
        acc0 = __builtin_amdgcn_mfma_f32_16x16x32_f16(a, v0, acc0, 0, 0, 0);
        acc1 = __builtin_amdgcn_mfma_f32_16x16x32_f16(a, v1, acc1, 0, 0, 0);
    }
    int fo = wave * 16 + (lane >> 4) * 4;
    int rowg = b * N_ + row0;
    h4 o0, o1;
    o0[0] = (_Float16)acc0[0]; o0[1] = (_Float16)acc0[1];
    o0[2] = (_Float16)acc0[2]; o0[3] = (_Float16)acc0[3];
    o1[0] = (_Float16)acc1[0]; o1[1] = (_Float16)acc1[1];
    o1[2] = (_Float16)acc1[2]; o1[3] = (_Float16)acc1[3];
    *(h4*)(out + (size_t)(rowg + lm) * 64 + fo) = o0;
    *(h4*)(out + (size_t)(rowg + 16 + lm) * 64 + fo) = o1;
}

// ---------------- conv2 gather + fused BN-stats partials --------------------
__global__ __launch_bounds__(256, 8) void k_gat(
        const int* __restrict__ cnt, const unsigned short* __restrict__ csr,
        const _Float16* __restrict__ z, const float* __restrict__ degIr,
        const float* __restrict__ bias, _Float16* __restrict__ out16,
        float* __restrict__ pstat) {
    __shared__ float sS[4][64];
    __shared__ float sQ[4][64];
    int t = threadIdx.x;
    int lane = t & 63;
    int wave = t >> 6;
    int c8 = lane & 7;
    int b = blockIdx.x & 7;
    int row = (blockIdx.x >> 3) * 32 + wave * 8 + (lane >> 3);
    int wid = b * N_ + row;
    const _Float16* zb = z + (size_t)b * NF_;
    int lb = lane & 56;
    int ho = c8 * 8;

    int n = cnt[wid];
    if (n > CAP_) n = CAP_;
    size_t cb = (size_t)wid * CAP_;
    uint4 ev = {0u, 0u, 0u, 0u};
    if (c8 * 8 < n) ev = *(const uint4*)(csr + cb + c8 * 8);
    int m = n;
    m = max(m, __shfl_xor(m, 8));
    m = max(m, __shfl_xor(m, 16));
    m = max(m, __shfl_xor(m, 32));

    float af[8];
#pragma unroll
    for (int i = 0; i < 8; ++i) af[i] = 0.0f;
    GAT_SEG(0)
    if (m > 8)  GAT_SEG(8)
    if (m > 16) GAT_SEG(16)
    if (m > 24) GAT_SEG(24)
    if (m > 32) GAT_SEG(32)
    if (m > 40) GAT_SEG(40)

    float dIr = degIr[wid];
    float4 bv0 = *(const float4*)(bias + ho);
    float4 bv1 = *(const float4*)(bias + ho + 4);
    float bb[8] = {bv0.x, bv0.y, bv0.z, bv0.w, bv1.x, bv1.y, bv1.z, bv1.w};
    float vv[8];
    h8 ov;
#pragma unroll
    for (int i = 0; i < 8; ++i) {
        vv[i] = fmaf(af[i], dIr, bb[i]);
        ov[i] = (_Float16)vv[i];
    }
    *(h8*)(out16 + (size_t)wid * 64 + ho) = ov;
    float ssv[8], qqv[8];
#pragma unroll
    for (int i = 0; i < 8; ++i) { ssv[i] = vv[i]; qqv[i] = vv[i] * vv[i]; }
#pragma unroll
    for (int i = 0; i < 8; ++i) {
        ssv[i] += __shfl_xor(ssv[i], 8);  qqv[i] += __shfl_xor(qqv[i], 8);
        ssv[i] += __shfl_xor(ssv[i], 16); qqv[i] += __shfl_xor(qqv[i], 16);
        ssv[i] += __shfl_xor(ssv[i], 32); qqv[i] += __shfl_xor(qqv[i], 32);
    }
    if (lane < 8) {
#pragma unroll
        for (int i = 0; i < 8; ++i) {
            sS[wave][lane * 8 + i] = ssv[i];
            sQ[wave][lane * 8 + i] = qqv[i];
        }
    }
    __syncthreads();
    if (t < 64) {
        float s_ = sS[0][t] + sS[1][t] + sS[2][t] + sS[3][t];
        float q_ = sQ[0][t] + sQ[1][t] + sQ[2][t] + sQ[3][t];
        pstat[(size_t)blockIdx.x * 128 + t] = s_;
        pstat[(size_t)blockIdx.x * 128 + 64 + t] = q_;
    }
}

// ---------------- reduce stats partials: [4096][128] -> stats2[32][128] -----
__global__ __launch_bounds__(256) void k_red(const float* __restrict__ part,
                                             float* __restrict__ stats2) {
    __shared__ float sred[256];
    int t = threadIdx.x;
    int half = t >> 7;   // 0/1
    int s = t & 127;     // stat id
    int r0 = blockIdx.x * (NSB_ / 32);  // 128 rows per block
    float acc = 0.0f;
    for (int k = 0; k < NSB_ / 32 / 2; ++k) {
        acc += part[(size_t)(r0 + k * 2 + half) * 128 + s];
    }
    sred[t] = acc;
    __syncthreads();
    if (t < 128) stats2[blockIdx.x * 128 + t] = sred[t] + sred[t + 128];
}

// ---------------- fused BN-coeff + BN-apply + final linear ------------------
// NOTE (R4): no threadfence-ticket fsum fusion — device-scope fence ~140 us.
__global__ __launch_bounds__(256) void k_final(
        const _Float16* __restrict__ h, const float* __restrict__ linW,
        const float* __restrict__ stats2, const float* __restrict__ gamma,
        const float* __restrict__ beta, float* __restrict__ pf) {
    __shared__ float pre[256];
    __shared__ float scs[64], shs[64];
    int t = threadIdx.x;
    {   // all 256 threads: stat u = t&127, j-half = t>>7 (16 iters each)
        int u = t & 127, jh = t >> 7;
        float a = 0.0f;
#pragma unroll
        for (int j = 0; j < 16; ++j) a += stats2[(jh * 16 + j) * 128 + u];
        pre[t] = a;
    }
    __syncthreads();
    if (t < 64) {
        float sum = pre[t] + pre[t + 128];
        float sq  = pre[t + 64] + pre[t + 192];
        float inv = 1.0f / (float)BN_;
        float mean = sum * inv;
        float var  = sq * inv - mean * mean;
        float s = gamma[t] * rsqrtf(var + EPS_);
        scs[t] = s;
        shs[t] = beta[t] - mean * s;
    }
    __syncthreads();

    int lane = t & 63;
    int wv = t >> 6;
    int b0 = wv * 2, b1 = wv * 2 + 1;
    int base = blockIdx.x * (NF_ / NFB_);  // 1024 per block
    float4 s4  = *(const float4*)&scs[(lane & 15) * 4];
    float4 sh4 = *(const float4*)&shs[(lane & 15) * 4];
    float acc[C_][2];
#pragma unroll
    for (int c = 0; c < C_; ++c) { acc[c][0] = 0.0f; acc[c][1] = 0.0f; }

#pragma unroll
    for (int k = 0; k < 4; ++k) {
        int i = base + k * 256 + lane * 4;  // 4 consecutive channels/thread
        h4 ha = *(const h4*)(h + (size_t)b0 * NF_ + i);
        h4 hb = *(const h4*)(h + (size_t)b1 * NF_ + i);
        float h0[4], h1[4];
        h0[0] = fmaf((float)ha[0], s4.x, sh4.x);
        h0[1] = fmaf((float)ha[1], s4.y, sh4.y);
        h0[2] = fmaf((float)ha[2], s4.z, sh4.z);
        h0[3] = fmaf((float)ha[3], s4.w, sh4.w);
        h1[0] = fmaf((float)hb[0], s4.x, sh4.x);
        h1[1] = fmaf((float)hb[1], s4.y, sh4.y);
        h1[2] = fmaf((float)hb[2], s4.z, sh4.z);
        h1[3] = fmaf((float)hb[3], s4.w, sh4.w);
#pragma unroll
        for (int c = 0; c < C_; ++c) {
            float4 w4 = *(const float4*)(linW + (size_t)c * NF_ + i);
            float a0 = acc[c][0], a1 = acc[c][1];
            a0 = fmaf(h0[0], w4.x, a0); a0 = fmaf(h0[1], w4.y, a0);
            a0 = fmaf(h0[2], w4.z, a0); a0 = fmaf(h0[3], w4.w, a0);
            a1 = fmaf(h1[0], w4.x, a1); a1 = fmaf(h1[1], w4.y, a1);
            a1 = fmaf(h1[2], w4.z, a1); a1 = fmaf(h1[3], w4.w, a1);
            acc[c][0] = a0; acc[c][1] = a1;
        }
    }

#pragma unroll
    for (int c = 0; c < C_; ++c) {
#pragma unroll
        for (int j = 0; j < 2; ++j) {
            float v = acc[c][j];
            v += __shfl_down(v, 32);
            v += __shfl_down(v, 16);
            v += __shfl_down(v, 8);
            v += __shfl_down(v, 4);
            v += __shfl_down(v, 2);
            v += __shfl_down(v, 1);
            acc[c][j] = v;
        }
    }
    if (lane == 0) {
        float* p = pf + (size_t)blockIdx.x * 80;
#pragma unroll
        for (int c = 0; c < C_; ++c) {
            p[b0 * C_ + c] = acc[c][0];
            p[b1 * C_ + c] = acc[c][1];
        }
    }
}

// ---------------- final sum: pf[1024][80] -> out[80] ------------------------
__global__ __launch_bounds__(64) void k_fsum(const float* __restrict__ pf,
                                             const float* __restrict__ linb,
                                             float* __restrict__ out) {
    int o = blockIdx.x;        // 0..79 = b*10+c
    int lane = threadIdx.x;
    float acc = 0.0f;
#pragma unroll
    for (int k = 0; k < 16; ++k) {
        acc += pf[(size_t)(k * 64 + lane) * 80 + o];
    }
    acc += __shfl_down(acc, 32);
    acc += __shfl_down(acc, 16);
    acc += __shfl_down(acc, 8);
    acc += __shfl_down(acc, 4);
    acc += __shfl_down(acc, 2);
    acc += __shfl_down(acc, 1);
    if (lane == 0) out[o] = acc + linb[o % C_];
}

extern "C" void kernel_launch(void* const* d_in, const int* in_sizes, int n_in,
                              void* d_out, int out_size, void* d_ws, size_t ws_size,
                              hipStream_t stream) {
    const float* x        = (const float*)d_in[0];
    const int*   edge_src = (const int*)d_in[1];
    const int*   edge_dst = (const int*)d_in[2];
    const float* W1       = (const float*)d_in[3];
    const float* b1       = (const float*)d_in[4];
    const float* W2       = (const float*)d_in[5];
    const float* b2       = (const float*)d_in[6];
    const float* gamma    = (const float*)d_in[7];
    const float* beta     = (const float*)d_in[8];
    const float* linW     = (const float*)d_in[9];
    const float* linb     = (const float*)d_in[10];
    float* out = (float*)d_out;

    char* w = (char*)d_ws;
    float* degOr = (float*)w;           w += BN_ * 4;
    float* degIr = (float*)w;           w += BN_ * 4;
    int*   cntI  = (int*)w;             w += BN_ * 4;
    unsigned short* csr = (unsigned short*)w; w += (size_t)BN_ * CAP_ * 2;
    _Float16* z1   = (_Float16*)w;      w += (size_t)BNF_ * 2;
    _Float16* z2   = (_Float16*)w;      w += (size_t)BNF_ * 2;  // must not alias z1
    _Float16* h2h  = (_Float16*)w;      w += (size_t)BNF_ * 2;
    unsigned int* partO   = (unsigned int*)w;  w += (size_t)B_ * NCH_ * NW_ * 4;
    unsigned int* partI   = (unsigned int*)w;  w += (size_t)B_ * NCH_ * NW_ * 4;
    unsigned int* baseArr = (unsigned int*)w;  w += (size_t)B_ * NCH_ * NW_ * 4;
    float* partStats = (float*)w;       w += (size_t)NSB_ * 128 * 4;
    float* stats2 = (float*)w;          w += 32 * 128 * 4;
    float* pf    = (float*)w;           w += (size_t)NFB_ * 80 * 4;
    _Float16* Wt1 = (_Float16*)w;       w += 4096 * 2;
    _Float16* Wt2 = (_Float16*)w;       w += 4096 * 2;

    // CSR build + degrees (W-transpose prep folded into k_count tail blocks)
    k_count<<<B_ * NCH_ + 16, 256, 0, stream>>>(edge_src, edge_dst, partO, partI,
                                                W1, W2, Wt1, Wt2);
    k_offsets<<<BN_ / 4 / 256, 256, 0, stream>>>(partO, partI, baseArr, degOr, degIr, cntI);

    // Co-scheduled: CSR fill (blocks 0..255) || conv1 mm (blocks 256..2303)
    k_fillmm<<<B_ * NCH_ + BN_ / 64, 256, 0, stream>>>(edge_src, edge_dst, baseArr,
                                                       csr, x, Wt1, degOr, z1);

    // fused conv1-gather + conv2-mm: z2 = fp16(h1 @ W2)
    k_gmm<<<BN_ / 32, 256, 0, stream>>>(cntI, csr, z1, degIr, degOr, b1, Wt2, z2);
    // conv2 gather: h2 = fp16(gather(z2)*dIr + b2) + BN-stats partials
    k_gat<<<BN_ / 32, 256, 0, stream>>>(cntI, csr, z2, degIr, b2, h2h, partStats);

    // BN stats reduce + fused BN/linear + final sum
    k_red<<<32, 256, 0, stream>>>(partStats, stats2);
    k_final<<<NFB_, 256, 0, stream>>>(h2h, linW, stats2, gamma, beta, pf);
    k_fsum<<<80, 64, 0, stream>>>(pf, linb, out);
}